// Round 5
// baseline (1184.990 us; speedup 1.0000x reference)
//
#include <hip/hip_runtime.h>
#include <hip/hip_bf16.h>

#define BB 128
#define TT 512
#define EE 128
#define HH 256
#define MM 1024
#define CC 5

typedef _Float16 h2 __attribute__((ext_vector_type(2)));
typedef __fp16 f16x2 __attribute__((ext_vector_type(2)));
typedef __fp16 f16x8 __attribute__((ext_vector_type(8)));
typedef float  f32x4 __attribute__((ext_vector_type(4)));

// pack 8 f32 -> 8 f16 (one MFMA operand fragment)
__device__ inline f16x8 pack8(float4 lo, float4 hi) {
    union { f16x2 h[4]; f16x8 v; } u;
    u.h[0] = __builtin_amdgcn_cvt_pkrtz(lo.x, lo.y);
    u.h[1] = __builtin_amdgcn_cvt_pkrtz(lo.z, lo.w);
    u.h[2] = __builtin_amdgcn_cvt_pkrtz(hi.x, hi.y);
    u.h[3] = __builtin_amdgcn_cvt_pkrtz(hi.z, hi.w);
    return u.v;
}

// 5-instr tanh: e = 2^(x*2*log2e); 1 - 2/(e+1)
__device__ inline float fast_tanh(float x) {
    float e = __builtin_amdgcn_exp2f(x * 2.8853900817779268f);
    return 1.0f - 2.0f / (e + 1.0f);
}

// bijective LDS swizzle for H tiles (verified R10)
#define SWZ(m) ((((m) & 7) << 4) ^ (((m) & 8) << 2))

// ---------------------------------------------------------------------------
// K (R11): FULLY FUSED embed + scan + MLP head. 8 blocks x 512 thr; block
// owns 16 batch rows. Per step, in ONE accumulator:
//   acc = bias(+b_ih+b_hh) ; acc += emb[x_t] @ W_ih^T (4 MFMA, h-independent,
//   issues during af ds_read latency) ; acc += H @ W_hh^T (8 MFMA, split
//   into two 6-deep chains ac0/ac1, merged with v_add) ; h = tanh(acc).
// u workspace GONE (k_embed deleted): no 32MB write, no 20MB read, no
// 2048-block dispatch. emb rows prefetched 2 steps ahead from global (L3-
// resident, 65MB); token indices from a 32KB LDS x-slab, read one step ahead
// of the loads so PF has no in-step lgkm dependency.
// Layouts (m89/m120-verified): A[m=lane&15][k=quad*8+j],
// B[k=quad*8+j][n=lane&15], D col=lane&15 row=quad*4+reg.
// ---------------------------------------------------------------------------
__global__ __launch_bounds__(512, 1)
void k_fused(const int* __restrict__ x, const int* __restrict__ lengths,
             const float* __restrict__ emb,
             const float* __restrict__ W_ih, const float* __restrict__ W_hh,
             const float* __restrict__ b_ih, const float* __restrict__ b_hh,
             const float* __restrict__ W0, const float* __restrict__ b0,
             const float* __restrict__ W1, const float* __restrict__ b1,
             float* __restrict__ out)
{
    const int bB   = blockIdx.x * 16;     // first batch row of this block
    const int tid  = threadIdx.x;
    const int wv   = tid >> 6;            // wave 0..7 -> channels [32wv,32wv+32)
    const int lane = tid & 63;
    const int l15  = lane & 15;
    const int quad = lane >> 4;

    __shared__ __align__(16) char ldsHA[16 * 512];     // 8KB h[16][256] f16
    __shared__ __align__(16) char ldsHB[16 * 512];     // 8KB ping-pong
    __shared__ __align__(16) char ldsH1[16 * 2048];    // 32KB relu(h@W0^T) f16
    __shared__ int xs[TT * 16];                        // 32KB x-slab [t][row]
    __shared__ int slen[16];

    if (tid < 16) slen[tid] = lengths[bB + tid];

    // stage x rows (transposed: xs[t][r]) — coalesced global reads
    {
        const int r = tid >> 5;
        #pragma unroll
        for (int i = 0; i < 16; ++i) {
            const int c = (tid & 31) + i * 32;
            xs[c * 16 + r] = x[(size_t)(bB + r) * TT + c];
        }
    }

    // W_hh B-frags: bf_hh[ct][kc], n = 32*wv + 16*ct + l15, k = 32*kc+8*quad+j
    f16x8 bf_hh[2][8];
    #pragma unroll
    for (int ct = 0; ct < 2; ++ct) {
        const int n = 32 * wv + 16 * ct + l15;
        const float* wp = W_hh + (size_t)n * HH;
        #pragma unroll
        for (int kc = 0; kc < 8; ++kc) {
            const float4* p = (const float4*)(wp + 32 * kc + 8 * quad);
            bf_hh[ct][kc] = pack8(p[0], p[1]);
        }
    }
    // W_ih B-frags (K=128): bf_ih[ct][kc], kc<4
    f16x8 bf_ih[2][4];
    float biasv[2];
    #pragma unroll
    for (int ct = 0; ct < 2; ++ct) {
        const int n = 32 * wv + 16 * ct + l15;
        const float* wp = W_ih + (size_t)n * EE;
        #pragma unroll
        for (int kc = 0; kc < 4; ++kc) {
            const float4* p = (const float4*)(wp + 32 * kc + 8 * quad);
            bf_ih[ct][kc] = pack8(p[0], p[1]);
        }
        biasv[ct] = b_ih[n] + b_hh[n];
    }

    // zero h buffer A
    ((float4*)ldsHA)[tid] = (float4){0.f, 0.f, 0.f, 0.f};
    __syncthreads();

    int maxlen = 0;
    #pragma unroll
    for (int i = 0; i < 16; ++i) maxlen = max(maxlen, slen[i]);
    int start[4];
    #pragma unroll
    for (int rg = 0; rg < 4; ++rg) {
        int L = slen[quad * 4 + rg];
        start[rg] = (L >= TT) ? 0 : (TT - L);
    }
    const int t0 = (TT - maxlen) & ~1;    // even-aligned start

    // loop-invariant LDS offsets (verified R10)
    int rdoff[8];
    #pragma unroll
    for (int kc = 0; kc < 8; ++kc)
        rdoff[kc] = (l15 * 512 + kc * 64 + quad * 16) ^ SWZ(l15);
    int wroff[8];
    #pragma unroll
    for (int ct = 0; ct < 2; ++ct)
        #pragma unroll
        for (int rg = 0; rg < 4; ++rg) {
            const int m = quad * 4 + rg;
            wroff[ct * 4 + rg] = (m * 512 + (32 * wv + 16 * ct + l15) * 2) ^ SWZ(m);
        }

    // token read (clamped); per-lane row = l15 (quad-redundant broadcast)
#define XTOK(T_) xs[((((T_) < TT) ? (T_) : (TT - 1)) << 4) + l15]

    // issue 8 global_load_dwordx4 of emb row TOK_ into PF_ (f32, this lane's
    // quad segment: floats k = 32kc + 8quad + 0..7)
#define EPF(PF_, TOK_) {                                                     \
        const char* eb_ = (const char*)emb +                                 \
            (((size_t)(unsigned)(TOK_)) << 9) + (quad << 5);                 \
        _Pragma("unroll")                                                    \
        for (int kc_ = 0; kc_ < 4; ++kc_) {                                  \
            PF_[2 * kc_]     = *(const float4*)(eb_ + kc_ * 128);            \
            PF_[2 * kc_ + 1] = *(const float4*)(eb_ + kc_ * 128 + 16);       \
        }                                                                    \
    }

    float4 pfA[8], pfB[8];                 // compile-time indexed ONLY
    int tokA, tokB;
    {
        const int ta = XTOK(t0), tb = XTOK(t0 + 1);
        EPF(pfA, ta);
        EPF(pfB, tb);
        tokA = XTOK(t0 + 2);
        tokB = XTOK(t0 + 3);
    }

#define RSTEP(SRC, DST, PF_, TOK_, T_) {                                     \
        f16x8 ae_[4];                                                        \
        _Pragma("unroll")                                                    \
        for (int kc_ = 0; kc_ < 4; ++kc_)                                    \
            ae_[kc_] = pack8(PF_[2 * kc_], PF_[2 * kc_ + 1]);                \
        EPF(PF_, TOK_);                    /* refill for T_+2 */             \
        TOK_ = XTOK((T_) + 4);             /* token for T_+4  */             \
        f16x8 af_[8];                                                        \
        _Pragma("unroll")                                                    \
        for (int kc_ = 0; kc_ < 8; ++kc_)                                    \
            af_[kc_] = *(const f16x8*)(SRC + rdoff[kc_]);                    \
        f32x4 ac0_[2], ac1_[2];                                              \
        _Pragma("unroll")                                                    \
        for (int ct_ = 0; ct_ < 2; ++ct_) {                                  \
            ac0_[ct_] = (f32x4){biasv[ct_], biasv[ct_], biasv[ct_],          \
                                biasv[ct_]};                                 \
            ac1_[ct_] = (f32x4){0.f, 0.f, 0.f, 0.f};                         \
        }                                                                    \
        /* emb part: h-independent, hides under af ds_read latency */        \
        _Pragma("unroll")                                                    \
        for (int kc_ = 0; kc_ < 2; ++kc_)                                    \
            _Pragma("unroll")                                                \
            for (int ct_ = 0; ct_ < 2; ++ct_) {                              \
                ac0_[ct_] = __builtin_amdgcn_mfma_f32_16x16x32_f16(          \
                    ae_[kc_], bf_ih[ct_][kc_], ac0_[ct_], 0, 0, 0);          \
                ac1_[ct_] = __builtin_amdgcn_mfma_f32_16x16x32_f16(          \
                    ae_[kc_ + 2], bf_ih[ct_][kc_ + 2], ac1_[ct_], 0, 0, 0);  \
            }                                                                \
        /* h part: two 4-deep chains per ct */                               \
        _Pragma("unroll")                                                    \
        for (int kc_ = 0; kc_ < 4; ++kc_)                                    \
            _Pragma("unroll")                                                \
            for (int ct_ = 0; ct_ < 2; ++ct_) {                              \
                ac0_[ct_] = __builtin_amdgcn_mfma_f32_16x16x32_f16(          \
                    af_[kc_], bf_hh[ct_][kc_], ac0_[ct_], 0, 0, 0);          \
                ac1_[ct_] = __builtin_amdgcn_mfma_f32_16x16x32_f16(          \
                    af_[kc_ + 4], bf_hh[ct_][kc_ + 4], ac1_[ct_], 0, 0, 0);  \
            }                                                                \
        _Pragma("unroll")                                                    \
        for (int ct_ = 0; ct_ < 2; ++ct_)                                    \
            _Pragma("unroll")                                                \
            for (int rg_ = 0; rg_ < 4; ++rg_) {                              \
                const float v_ = ac0_[ct_][rg_] + ac1_[ct_][rg_];            \
                const bool act_ = (T_) >= start[rg_];                        \
                const float h_ = act_ ? fast_tanh(v_) : 0.f;                 \
                *(_Float16*)(DST + wroff[ct_ * 4 + rg_]) = (_Float16)h_;     \
            }                                                                \
        __builtin_amdgcn_sched_barrier(0);                                   \
        asm volatile("s_waitcnt lgkmcnt(0)");                                \
        __builtin_amdgcn_s_barrier();                                        \
        __builtin_amdgcn_sched_barrier(0);                                   \
    }

    for (int t = t0; t < TT; t += 2) {
        RSTEP(ldsHA, ldsHB, pfA, tokA, t);      // even: A -> B
        RSTEP(ldsHB, ldsHA, pfB, tokB, t + 1);  // odd:  B -> A
    }
    // final h state is in ldsHA (even # of steps; zeroed A if no steps)

    // ---- head: H1 = relu(h @ W0^T + b0), 16x1024, via MFMA ----
    {
        f16x8 af[8];
        #pragma unroll
        for (int kc = 0; kc < 8; ++kc)
            af[kc] = *(const f16x8*)(ldsHA + rdoff[kc]);

        #pragma unroll
        for (int j = 0; j < 8; ++j) {
            const int n = 128 * wv + 16 * j + l15;
            const float bias = b0[n];
            f32x4 acc = (f32x4){bias, bias, bias, bias};
            const float* wp = W0 + (size_t)n * HH;
            #pragma unroll
            for (int kc = 0; kc < 8; ++kc) {
                const float4* pp = (const float4*)(wp + 32 * kc + 8 * quad);
                f16x8 bw = pack8(pp[0], pp[1]);
                acc = __builtin_amdgcn_mfma_f32_16x16x32_f16(af[kc], bw, acc, 0, 0, 0);
            }
            #pragma unroll
            for (int rg = 0; rg < 4; ++rg) {
                const int m = quad * 4 + rg;
                *(_Float16*)(ldsH1 + ((m * 2048 + n * 2) ^ ((m & 7) << 4)))
                    = (_Float16)fmaxf(acc[rg], 0.f);
            }
        }
    }
    __syncthreads();

    // ---- W1 (1024->5) + relu + log_softmax on VALU ----
    {
        const int m  = tid >> 5;          // batch row 0..15
        const int sl = tid & 31;          // 32-lane k-split
        float pc[CC] = {0.f, 0.f, 0.f, 0.f, 0.f};
        #pragma unroll
        for (int z = 0; z < 4; ++z) {
            const int kb = sl * 64 + z * 16;   // byte offset of 8 f16
            f16x8 hv8 = *(const f16x8*)(ldsH1 + ((m * 2048 + kb) ^ ((m & 7) << 4)));
            float he[8];
            #pragma unroll
            for (int e = 0; e < 8; ++e) he[e] = (float)hv8[e];
            #pragma unroll
            for (int c = 0; c < CC; ++c) {
                const float* w1p = W1 + (size_t)c * MM + sl * 32 + z * 8;
                float4 wa = ((const float4*)w1p)[0];
                float4 wb = ((const float4*)w1p)[1];
                pc[c] += he[0] * wa.x + he[1] * wa.y + he[2] * wa.z + he[3] * wa.w
                       + he[4] * wb.x + he[5] * wb.y + he[6] * wb.z + he[7] * wb.w;
            }
        }
        #pragma unroll
        for (int c = 0; c < CC; ++c) {
            #pragma unroll
            for (int off = 16; off > 0; off >>= 1)
                pc[c] += __shfl_down(pc[c], off, 32);
        }
        if (sl == 0) {
            float v[CC];
            float mx = -1e30f;
            #pragma unroll
            for (int c = 0; c < CC; ++c) {
                v[c] = fmaxf(pc[c] + b1[c], 0.f);
                mx = fmaxf(mx, v[c]);
            }
            float se = 0.f;
            #pragma unroll
            for (int c = 0; c < CC; ++c) se += __expf(v[c] - mx);
            const float lse = mx + __logf(se);
            #pragma unroll
            for (int c = 0; c < CC; ++c)
                out[(size_t)(bB + m) * CC + c] = v[c] - lse;
        }
    }
}

// ---------------------------------------------------------------------------
extern "C" void kernel_launch(void* const* d_in, const int* in_sizes, int n_in,
                              void* d_out, int out_size, void* d_ws, size_t ws_size,
                              hipStream_t stream) {
    const int*   x       = (const int*)d_in[0];
    const int*   lengths = (const int*)d_in[1];
    const float* emb     = (const float*)d_in[2];
    const float* W_ih    = (const float*)d_in[3];
    const float* W_hh    = (const float*)d_in[4];
    const float* b_ih    = (const float*)d_in[5];
    const float* b_hh    = (const float*)d_in[6];
    const float* W0      = (const float*)d_in[7];
    const float* b0      = (const float*)d_in[8];
    const float* W1      = (const float*)d_in[9];
    const float* b1      = (const float*)d_in[10];
    float* out = (float*)d_out;

    // workspace unused (u eliminated)
    (void)d_ws; (void)ws_size;

    k_fused<<<BB / 16, 512, 0, stream>>>(x, lengths, emb, W_ih, W_hh,
                                         b_ih, b_hh, W0, b0, W1, b1, out);
}

// Round 6
// 945.671 us; speedup vs baseline: 1.2531x; 1.2531x over previous
//
#include <hip/hip_runtime.h>
#include <hip/hip_bf16.h>

#define BB 128
#define TT 512
#define EE 128
#define HH 256
#define MM 1024
#define CC 5

typedef _Float16 h2 __attribute__((ext_vector_type(2)));
typedef __fp16 f16x2 __attribute__((ext_vector_type(2)));
typedef __fp16 f16x8 __attribute__((ext_vector_type(8)));
typedef float  f32x4 __attribute__((ext_vector_type(4)));

// pack 8 f32 -> 8 f16 (one MFMA operand fragment)
__device__ inline f16x8 pack8(float4 lo, float4 hi) {
    union { f16x2 h[4]; f16x8 v; } u;
    u.h[0] = __builtin_amdgcn_cvt_pkrtz(lo.x, lo.y);
    u.h[1] = __builtin_amdgcn_cvt_pkrtz(lo.z, lo.w);
    u.h[2] = __builtin_amdgcn_cvt_pkrtz(hi.x, hi.y);
    u.h[3] = __builtin_amdgcn_cvt_pkrtz(hi.z, hi.w);
    return u.v;
}

// 5-instr tanh: e = 2^(x*2*log2e); 1 - 2/(e+1)
__device__ inline float fast_tanh(float x) {
    float e = __builtin_amdgcn_exp2f(x * 2.8853900817779268f);
    return 1.0f - 2.0f / (e + 1.0f);
}

// bijective LDS swizzle for H tiles (verified R10)
#define SWZ(m) ((((m) & 7) << 4) ^ (((m) & 8) << 2))

// ---------------------------------------------------------------------------
// K1 (MFMA GEMM): u[tok][ch] = bias[ch] + emb[x[tok]] @ W_ih^T, f16 out.
// (unchanged from R10 — verified; early-exit for fully-inactive tiles)
// Layouts (m89/m120-verified): A[m=lane&15][k=quad*8+j],
// B[k=quad*8+j][n=lane&15], D col=lane&15 row=quad*4+reg.
// ---------------------------------------------------------------------------
__global__ __launch_bounds__(256, 2)
void k_embed(const int* __restrict__ x, const int* __restrict__ lengths,
             const float* __restrict__ emb, const float* __restrict__ W_ih,
             const float* __restrict__ b_ih, const float* __restrict__ b_hh,
             _Float16* __restrict__ u)
{
    const int tb   = blockIdx.x;        // 32-token tile
    {
        const int bb   = tb >> 4;
        const int tend = ((tb & 15) << 5) + 31;
        if (tend < TT - lengths[bb]) return;   // fully inactive -> skip
    }
    const int tid  = threadIdx.x;
    const int wv   = tid >> 6;
    const int lane = tid & 63;
    const int l15  = lane & 15;
    const int quad = lane >> 4;

    __shared__ __align__(16) char ldsA[32 * 256];   // 8KB f16 A-stage
    __shared__ __align__(16) char ldsO[32 * 512];   // 16KB f16 output tile

    f16x8 bf[4][4];
    float bias[4];
    #pragma unroll
    for (int ct = 0; ct < 4; ++ct) {
        const int n = 64 * wv + 16 * ct + l15;
        const float* wp = W_ih + (size_t)n * EE;
        #pragma unroll
        for (int kc = 0; kc < 4; ++kc) {
            const float4* p = (const float4*)(wp + 32 * kc + 8 * quad);
            bf[ct][kc] = pack8(p[0], p[1]);
        }
        bias[ct] = b_ih[n] + b_hh[n];
    }

    {
        const int r = tid >> 3;          // row 0..31
        const int s = tid & 7;           // 16-float segment
        const int tok = x[tb * 32 + r];
        const float4* ep = (const float4*)(emb + (size_t)tok * EE + 16 * s);
        float4 a = ep[0], b = ep[1], c = ep[2], d = ep[3];
        *(f16x8*)(ldsA + r * 256 + 32 * s)      = pack8(a, b);
        *(f16x8*)(ldsA + r * 256 + 32 * s + 16) = pack8(c, d);
    }
    __syncthreads();

    f32x4 acc[2][4];
    #pragma unroll
    for (int rt = 0; rt < 2; ++rt)
        #pragma unroll
        for (int ct = 0; ct < 4; ++ct)
            acc[rt][ct] = (f32x4){bias[ct], bias[ct], bias[ct], bias[ct]};

    #pragma unroll
    for (int kc = 0; kc < 4; ++kc) {
        const int ko = (32 * kc + 8 * quad) * 2;
        f16x8 a0 = *(const f16x8*)(ldsA + (l15)      * 256 + ko);
        f16x8 a1 = *(const f16x8*)(ldsA + (16 + l15) * 256 + ko);
        #pragma unroll
        for (int ct = 0; ct < 4; ++ct) {
            acc[0][ct] = __builtin_amdgcn_mfma_f32_16x16x32_f16(a0, bf[ct][kc], acc[0][ct], 0, 0, 0);
            acc[1][ct] = __builtin_amdgcn_mfma_f32_16x16x32_f16(a1, bf[ct][kc], acc[1][ct], 0, 0, 0);
        }
    }

    #pragma unroll
    for (int rt = 0; rt < 2; ++rt) {
        #pragma unroll
        for (int ct = 0; ct < 4; ++ct) {
            const int chb = (64 * wv + 16 * ct + l15) * 2;
            #pragma unroll
            for (int rg = 0; rg < 4; ++rg) {
                const int tok = 16 * rt + 4 * quad + rg;
                *(_Float16*)(ldsO + tok * 512 + chb) = (_Float16)acc[rt][ct][rg];
            }
        }
    }
    __syncthreads();

    {
        char* dst = (char*)u + (size_t)tb * 16384 + tid * 64;
        const char* src = ldsO + tid * 64;
        #pragma unroll
        for (int q = 0; q < 4; ++q)
            *(float4*)(dst + 16 * q) = *(const float4*)(src + 16 * q);
    }
}

// ---------------------------------------------------------------------------
// K2 (R12): scan re-shaped to 16 blocks x 4 waves x 8 batch rows.
//  - 1 wave/SIMD (kills the 2-wave barrier-lockstep convoy of R10)
//  - per wave: 64 cols = 4 col-tiles; K=256 split into TWO 4-deep MFMA
//    chains per tile (ac0: kc0-3, ac1: kc4-7, one v_add merge) -> critical
//    path 4xL not 8xL
//  - barrier syncs 4 waves; 16 CUs active
//  - H tile stays 16 rows (rows 8-15 zeroed once, never written: their D
//    rows are computed but discarded -> correctness by construction)
//  - u gather + tanh + h-writes confined to quads 0-1 (rows 0-7)
// Everything else (swizzle, offsets, barrier form, 2-step u prefetch,
// fused head) carried over from the verified R10.
// ---------------------------------------------------------------------------
__global__ __launch_bounds__(256, 1)
void k_rnn_head(const int* __restrict__ lengths, const float* __restrict__ W_hh,
                const _Float16* __restrict__ u,
                const float* __restrict__ W0, const float* __restrict__ b0,
                const float* __restrict__ W1, const float* __restrict__ b1,
                float* __restrict__ out)
{
    const int bB   = blockIdx.x * 8;      // first batch row of this block
    const int tid  = threadIdx.x;
    const int wv   = tid >> 6;            // wave 0..3 -> cols [64wv, 64wv+64)
    const int lane = tid & 63;
    const int l15  = lane & 15;
    const int quad = lane >> 4;

    __shared__ __align__(16) char ldsHA[16 * 512];     // 8KB h[16][256] f16
    __shared__ __align__(16) char ldsHB[16 * 512];     // 8KB ping-pong
    __shared__ __align__(16) char ldsH1[8 * 2048];     // 16KB relu(h@W0^T) f16
    __shared__ int slen[8];

    if (tid < 8) slen[tid] = lengths[bB + tid];

    // W_hh B-frags: bf_hh[ct][kc], n = 64*wv + 16*ct + l15, k = 32*kc+8*quad+j
    f16x8 bf_hh[4][8];
    #pragma unroll
    for (int ct = 0; ct < 4; ++ct) {
        const int n = 64 * wv + 16 * ct + l15;
        const float* wp = W_hh + (size_t)n * HH;
        #pragma unroll
        for (int kc = 0; kc < 8; ++kc) {
            const float4* p = (const float4*)(wp + 32 * kc + 8 * quad);
            bf_hh[ct][kc] = pack8(p[0], p[1]);
        }
    }

    // zero BOTH h buffers (rows 8-15 stay zero forever)
    ((float4*)ldsHA)[tid]       = (float4){0.f, 0.f, 0.f, 0.f};
    ((float4*)ldsHA)[tid + 256] = (float4){0.f, 0.f, 0.f, 0.f};
    ((float4*)ldsHB)[tid]       = (float4){0.f, 0.f, 0.f, 0.f};
    ((float4*)ldsHB)[tid + 256] = (float4){0.f, 0.f, 0.f, 0.f};
    __syncthreads();

    int maxlen = 0;
    #pragma unroll
    for (int i = 0; i < 8; ++i) maxlen = max(maxlen, slen[i]);
    int start[4];
    #pragma unroll
    for (int rg = 0; rg < 4; ++rg) {
        int L = slen[((quad & 1) * 4 + rg) & 7];   // valid for quads 0-1
        start[rg] = (L >= TT) ? 0 : (TT - L);
    }
    const int t0 = (TT - maxlen) & ~1;    // even-aligned start

    // loop-invariant LDS offsets
    int rdoff[8];
    #pragma unroll
    for (int kc = 0; kc < 8; ++kc)
        rdoff[kc] = (l15 * 512 + kc * 64 + quad * 16) ^ SWZ(l15);
    int wroff[16];                         // [ct*4+rg], rows m = quad*4+rg (<8)
    #pragma unroll
    for (int ct = 0; ct < 4; ++ct)
        #pragma unroll
        for (int rg = 0; rg < 4; ++rg) {
            const int m = (quad & 1) * 4 + rg;
            wroff[ct * 4 + rg] = (m * 512 + (64 * wv + 16 * ct + l15) * 2) ^ SWZ(m);
        }

    // u gather voffsets: [ct*4+rg], row m = (quad&1)*4+rg, ch = 64wv+16ct+l15
    int uvoffs[16];
    #pragma unroll
    for (int ct = 0; ct < 4; ++ct)
        #pragma unroll
        for (int rg = 0; rg < 4; ++rg)
            uvoffs[ct * 4 + rg] = (bB + (quad & 1) * 4 + rg) * (TT * HH * 2)
                                + (64 * wv + 16 * ct + l15) * 2;

    const char* ubytes = (const char*)u;
    _Float16 uvA[16], uvB[16];             // compile-time indexed ONLY
    #pragma unroll
    for (int i = 0; i < 16; ++i) { uvA[i] = (_Float16)0.f; uvB[i] = (_Float16)0.f; }

#define ULOAD(DST, T_) {                                                     \
        if (quad < 2) {                                                      \
            const int tcl_ = ((T_) < TT - 1) ? (T_) : (TT - 1);              \
            const char* up_ = ubytes +                                       \
                (size_t)(unsigned)__builtin_amdgcn_readfirstlane(tcl_ << 9); \
            _Pragma("unroll")                                                \
            for (int i_ = 0; i_ < 16; ++i_)                                  \
                DST[i_] = *(const _Float16*)(up_ + uvoffs[i_]);              \
        }                                                                    \
    }

    ULOAD(uvA, t0);
    ULOAD(uvB, t0 + 1);

#define RSTEP(SRC, DST, UV, T_) {                                            \
        f16x8 af_[8];                                                        \
        _Pragma("unroll")                                                    \
        for (int kc_ = 0; kc_ < 8; ++kc_)                                    \
            af_[kc_] = *(const f16x8*)(SRC + rdoff[kc_]);                    \
        f32x4 a0_[4], a1_[4];                                                \
        _Pragma("unroll")                                                    \
        for (int ct_ = 0; ct_ < 4; ++ct_) {                                  \
            _Pragma("unroll")                                                \
            for (int rg_ = 0; rg_ < 4; ++rg_)                                \
                a0_[ct_][rg_] = (float)UV[ct_ * 4 + rg_];                    \
            a1_[ct_] = (f32x4){0.f, 0.f, 0.f, 0.f};                          \
        }                                                                    \
        ULOAD(UV, (T_) + 2);              /* refill, consumed 2 steps on */  \
        /* 8 independent 4-deep chains (ac0: kc0-3, ac1: kc4-7) */           \
        _Pragma("unroll")                                                    \
        for (int kc_ = 0; kc_ < 4; ++kc_)                                    \
            _Pragma("unroll")                                                \
            for (int ct_ = 0; ct_ < 4; ++ct_) {                              \
                a0_[ct_] = __builtin_amdgcn_mfma_f32_16x16x32_f16(           \
                    af_[kc_], bf_hh[ct_][kc_], a0_[ct_], 0, 0, 0);           \
                a1_[ct_] = __builtin_amdgcn_mfma_f32_16x16x32_f16(           \
                    af_[kc_ + 4], bf_hh[ct_][kc_ + 4], a1_[ct_], 0, 0, 0);   \
            }                                                                \
        if (quad < 2) {                                                      \
            _Pragma("unroll")                                                \
            for (int ct_ = 0; ct_ < 4; ++ct_)                                \
                _Pragma("unroll")                                            \
                for (int rg_ = 0; rg_ < 4; ++rg_) {                          \
                    const float v_ = a0_[ct_][rg_] + a1_[ct_][rg_];          \
                    const bool act_ = (T_) >= start[rg_];                    \
                    const float h_ = act_ ? fast_tanh(v_) : 0.f;             \
                    *(_Float16*)(DST + wroff[ct_ * 4 + rg_]) = (_Float16)h_; \
                }                                                            \
        }                                                                    \
        __builtin_amdgcn_sched_barrier(0);                                   \
        asm volatile("s_waitcnt lgkmcnt(0)");                                \
        __builtin_amdgcn_s_barrier();                                        \
        __builtin_amdgcn_sched_barrier(0);                                   \
    }

    for (int t = t0; t < TT; t += 2) {
        RSTEP(ldsHA, ldsHB, uvA, t);      // even: A -> B
        RSTEP(ldsHB, ldsHA, uvB, t + 1);  // odd:  B -> A
    }
    // final h state is in ldsHA (even # of steps; zeroed A if no steps)

    // ---- head: H1 = relu(h @ W0^T + b0), 8x1024, via MFMA ----
    {
        f16x8 af[8];
        #pragma unroll
        for (int kc = 0; kc < 8; ++kc)
            af[kc] = *(const f16x8*)(ldsHA + rdoff[kc]);

        #pragma unroll
        for (int j = 0; j < 16; ++j) {
            const int n = 256 * wv + 16 * j + l15;
            const float bias = b0[n];
            f32x4 acc = (f32x4){bias, bias, bias, bias};
            const float* wp = W0 + (size_t)n * HH;
            #pragma unroll
            for (int kc = 0; kc < 8; ++kc) {
                const float4* pp = (const float4*)(wp + 32 * kc + 8 * quad);
                f16x8 bw = pack8(pp[0], pp[1]);
                acc = __builtin_amdgcn_mfma_f32_16x16x32_f16(af[kc], bw, acc, 0, 0, 0);
            }
            if (quad < 2) {
                #pragma unroll
                for (int rg = 0; rg < 4; ++rg) {
                    const int m = (quad & 1) * 4 + rg;
                    *(_Float16*)(ldsH1 + ((m * 2048 + n * 2) ^ ((m & 7) << 4)))
                        = (_Float16)fmaxf(acc[rg], 0.f);
                }
            }
        }
    }
    __syncthreads();

    // ---- W1 (1024->5) + relu + log_softmax on VALU ----
    {
        const int m  = tid >> 5;          // batch row 0..7
        const int sl = tid & 31;          // 32-lane k-split
        float pc[CC] = {0.f, 0.f, 0.f, 0.f, 0.f};
        #pragma unroll
        for (int z = 0; z < 4; ++z) {
            const int kb = sl * 64 + z * 16;   // byte offset of 8 f16
            f16x8 hv8 = *(const f16x8*)(ldsH1 + ((m * 2048 + kb) ^ ((m & 7) << 4)));
            float he[8];
            #pragma unroll
            for (int e = 0; e < 8; ++e) he[e] = (float)hv8[e];
            #pragma unroll
            for (int c = 0; c < CC; ++c) {
                const float* w1p = W1 + (size_t)c * MM + sl * 32 + z * 8;
                float4 wa = ((const float4*)w1p)[0];
                float4 wb = ((const float4*)w1p)[1];
                pc[c] += he[0] * wa.x + he[1] * wa.y + he[2] * wa.z + he[3] * wa.w
                       + he[4] * wb.x + he[5] * wb.y + he[6] * wb.z + he[7] * wb.w;
            }
        }
        #pragma unroll
        for (int c = 0; c < CC; ++c) {
            #pragma unroll
            for (int off = 16; off > 0; off >>= 1)
                pc[c] += __shfl_down(pc[c], off, 32);
        }
        if (sl == 0) {
            float v[CC];
            float mx = -1e30f;
            #pragma unroll
            for (int c = 0; c < CC; ++c) {
                v[c] = fmaxf(pc[c] + b1[c], 0.f);
                mx = fmaxf(mx, v[c]);
            }
            float se = 0.f;
            #pragma unroll
            for (int c = 0; c < CC; ++c) se += __expf(v[c] - mx);
            const float lse = mx + __logf(se);
            #pragma unroll
            for (int c = 0; c < CC; ++c)
                out[(size_t)(bB + m) * CC + c] = v[c] - lse;
        }
    }
}

// ---------------------------------------------------------------------------
extern "C" void kernel_launch(void* const* d_in, const int* in_sizes, int n_in,
                              void* d_out, int out_size, void* d_ws, size_t ws_size,
                              hipStream_t stream) {
    const int*   x       = (const int*)d_in[0];
    const int*   lengths = (const int*)d_in[1];
    const float* emb     = (const float*)d_in[2];
    const float* W_ih    = (const float*)d_in[3];
    const float* W_hh    = (const float*)d_in[4];
    const float* b_ih    = (const float*)d_in[5];
    const float* b_hh    = (const float*)d_in[6];
    const float* W0      = (const float*)d_in[7];
    const float* b0      = (const float*)d_in[8];
    const float* W1      = (const float*)d_in[9];
    const float* b1      = (const float*)d_in[10];
    float* out = (float*)d_out;

    // Workspace: u only — exactly BB*TT*HH*2 = 32 MiB.
    _Float16* u = (_Float16*)d_ws;

    k_embed   <<<(BB * TT) / 32, 256, 0, stream>>>(x, lengths, emb, W_ih, b_ih, b_hh, u);
    k_rnn_head<<<BB / 8, 256, 0, stream>>>(lengths, W_hh, u, W0, b0, W1, b1, out);
}

// Round 7
// 402.455 us; speedup vs baseline: 2.9444x; 2.3498x over previous
//
#include <hip/hip_runtime.h>
#include <hip/hip_bf16.h>

#define BB 128
#define TT 512
#define EE 128
#define HH 256
#define MM 1024
#define CC 5

typedef _Float16 h2 __attribute__((ext_vector_type(2)));
typedef __fp16 f16x2 __attribute__((ext_vector_type(2)));
typedef __fp16 f16x8 __attribute__((ext_vector_type(8)));
typedef float  f32x4 __attribute__((ext_vector_type(4)));

__device__ inline h2 mkh2(float a, float b) {
    return __builtin_bit_cast(h2, __builtin_amdgcn_cvt_pkrtz(a, b));
}

// pack 8 f32 -> 8 f16 (one MFMA operand fragment)
__device__ inline f16x8 pack8(float4 lo, float4 hi) {
    union { f16x2 h[4]; f16x8 v; } u;
    u.h[0] = __builtin_amdgcn_cvt_pkrtz(lo.x, lo.y);
    u.h[1] = __builtin_amdgcn_cvt_pkrtz(lo.z, lo.w);
    u.h[2] = __builtin_amdgcn_cvt_pkrtz(hi.x, hi.y);
    u.h[3] = __builtin_amdgcn_cvt_pkrtz(hi.z, hi.w);
    return u.v;
}

__device__ inline float dot2f(h2 a, h2 b, float c) {
#if __has_builtin(__builtin_amdgcn_fdot2)
    return __builtin_amdgcn_fdot2(a, b, c, false);
#else
    return c + (float)a.x * (float)b.x + (float)a.y * (float)b.y;
#endif
}

// Quad butterfly sum via DPP (VALU pipe, no LDS traffic).
__device__ inline float dpp_add4(float x) {
    int t = __builtin_amdgcn_update_dpp(0, __builtin_bit_cast(int, x), 0xB1, 0xF, 0xF, true);
    x += __builtin_bit_cast(float, t);
    t = __builtin_amdgcn_update_dpp(0, __builtin_bit_cast(int, x), 0x4E, 0xF, 0xF, true);
    x += __builtin_bit_cast(float, t);
    return x;
}

__device__ inline float fast_tanh(float x) {
    float e = __expf(2.0f * x);
    return 1.0f - 2.0f / (e + 1.0f);
}

// ---------------------------------------------------------------------------
// K1 (MFMA GEMM): u[tok][ch] = bias[ch] + emb[x[tok]] @ W_ih^T, f16 out.
// R13: early-exit for fully-inactive tiles (keeping the tile that contains
// t = T-len-1, needed by the even-rounded scan start) + ZERO-masking of
// inactive tokens in the writeout (u[t<T-len] == 0 exactly, so an early
// scan step computes tanh(0 + W*0) = 0 — harmless).
// Layouts (m89/m120-verified): A[m=lane&15][k=quad*8+j],
// B[k=quad*8+j][n=lane&15], D col=lane&15 row=quad*4+reg.
// ---------------------------------------------------------------------------
__global__ __launch_bounds__(256, 2)
void k_embed(const int* __restrict__ x, const int* __restrict__ lengths,
             const float* __restrict__ emb, const float* __restrict__ W_ih,
             const float* __restrict__ b_ih, const float* __restrict__ b_hh,
             _Float16* __restrict__ u)
{
    const int tb   = blockIdx.x;        // 32-token tile
    const int bb   = tb >> 4;
    const int len  = lengths[bb];
    {
        const int tend = ((tb & 15) << 5) + 31;
        if (tend < TT - len - 1) return;   // fully inactive (incl. pre-step)
    }
    const int tid  = threadIdx.x;
    const int wv   = tid >> 6;
    const int lane = tid & 63;
    const int l15  = lane & 15;
    const int quad = lane >> 4;

    __shared__ __align__(16) char ldsA[32 * 256];   // 8KB f16 A-stage
    __shared__ __align__(16) char ldsO[32 * 512];   // 16KB f16 output tile

    f16x8 bf[4][4];
    float bias[4];
    #pragma unroll
    for (int ct = 0; ct < 4; ++ct) {
        const int n = 64 * wv + 16 * ct + l15;
        const float* wp = W_ih + (size_t)n * EE;
        #pragma unroll
        for (int kc = 0; kc < 4; ++kc) {
            const float4* p = (const float4*)(wp + 32 * kc + 8 * quad);
            bf[ct][kc] = pack8(p[0], p[1]);
        }
        bias[ct] = b_ih[n] + b_hh[n];
    }

    {
        const int r = tid >> 3;          // row 0..31
        const int s = tid & 7;           // 16-float segment
        const int tok = x[tb * 32 + r];
        const float4* ep = (const float4*)(emb + (size_t)tok * EE + 16 * s);
        float4 a = ep[0], b = ep[1], c = ep[2], d = ep[3];
        *(f16x8*)(ldsA + r * 256 + 32 * s)      = pack8(a, b);
        *(f16x8*)(ldsA + r * 256 + 32 * s + 16) = pack8(c, d);
    }
    __syncthreads();

    f32x4 acc[2][4];
    #pragma unroll
    for (int rt = 0; rt < 2; ++rt)
        #pragma unroll
        for (int ct = 0; ct < 4; ++ct)
            acc[rt][ct] = (f32x4){bias[ct], bias[ct], bias[ct], bias[ct]};

    #pragma unroll
    for (int kc = 0; kc < 4; ++kc) {
        const int ko = (32 * kc + 8 * quad) * 2;
        f16x8 a0 = *(const f16x8*)(ldsA + (l15)      * 256 + ko);
        f16x8 a1 = *(const f16x8*)(ldsA + (16 + l15) * 256 + ko);
        #pragma unroll
        for (int ct = 0; ct < 4; ++ct) {
            acc[0][ct] = __builtin_amdgcn_mfma_f32_16x16x32_f16(a0, bf[ct][kc], acc[0][ct], 0, 0, 0);
            acc[1][ct] = __builtin_amdgcn_mfma_f32_16x16x32_f16(a1, bf[ct][kc], acc[1][ct], 0, 0, 0);
        }
    }

    #pragma unroll
    for (int rt = 0; rt < 2; ++rt) {
        #pragma unroll
        for (int ct = 0; ct < 4; ++ct) {
            const int chb = (64 * wv + 16 * ct + l15) * 2;
            #pragma unroll
            for (int rg = 0; rg < 4; ++rg) {
                const int tok = 16 * rt + 4 * quad + rg;
                *(_Float16*)(ldsO + tok * 512 + chb) = (_Float16)acc[rt][ct][rg];
            }
        }
    }
    __syncthreads();

    {
        // thread writes 64B of token (tid>>3); zero if token inactive
        const int tglob = ((tb & 15) << 5) + (tid >> 3);
        const bool act  = tglob >= TT - len;
        char* dst = (char*)u + (size_t)tb * 16384 + tid * 64;
        const char* src = ldsO + tid * 64;
        const float4 z = (float4){0.f, 0.f, 0.f, 0.f};
        #pragma unroll
        for (int q = 0; q < 4; ++q) {
            float4 v = *(const float4*)(src + 16 * q);
            *(float4*)(dst + 16 * q) = act ? v : z;
        }
    }
}

// ---------------------------------------------------------------------------
// K2 (R13): serial VALU scan (the verified R1 structure — best measured at
// 312us/1460cyc-per-step) + fused MLP head. One workgroup per batch element,
// split-K(4) + DPP, u staged in 64-step chunks (32KB LDS).
// R13 surgical changes vs R1:
//  - len rounded UP to even (len2); u is exactly 0 for t < T-len (k_embed
//    masks), so the extra leading step computes tanh(0+W*0)=0 — harmless.
//    => every chunk has an EVEN step count => inner loop unrolled x2 with
//    NAMED ping-pong buffers hA/hB (no runtime p index; rule #20).
//  - uv (this thread's u[t][tid]) prefetched ONE step ahead into named
//    registers uv0/uv1 — removes ~120cyc ds_read latency from the serial
//    per-step chain.
//  - inner-loop barrier: sched_barrier + lgkmcnt-only wait + s_barrier
//    (loop is LDS-only; verified form from R10).
// ---------------------------------------------------------------------------
__global__ __launch_bounds__(256, 1)
void k_rnn_head(const int* __restrict__ lengths, const float* __restrict__ W_hh,
                const _Float16* __restrict__ u,
                const float* __restrict__ W0, const float* __restrict__ b0,
                const float* __restrict__ W1, const float* __restrict__ b1,
                float* __restrict__ out)
{
    const int b = blockIdx.x;
    const int tid = threadIdx.x;
    const int kc = tid & 3;
    const int g  = tid >> 2;
    const int len = lengths[b];
    const int len2 = (len + 1) & ~1;              // even-rounded (<= TT)

    h2 w[4][32];
    #pragma unroll
    for (int m = 0; m < 4; ++m) {
        const float4* wr = (const float4*)(W_hh + (size_t)(4*g + m) * HH + kc*64);
        #pragma unroll
        for (int q = 0; q < 16; ++q) {
            float4 v = wr[q];
            w[m][2*q]   = mkh2(v.x, v.y);
            w[m][2*q+1] = mkh2(v.z, v.w);
        }
    }

    __shared__ __align__(16) char hbufA[512];       // 256 f16 (b128-read)
    __shared__ __align__(16) char hbufB[512];
    __shared__ __align__(16) char ubuf[64 * 512];   // 64 steps x 256ch x 2B
    __shared__ __align__(16) float sh[HH];          // head: h row (f32)
    __shared__ __align__(16) float sh1[MM];         // head: relu(h@W0^T+b0)
    __shared__ float sred[CC][4];
    __shared__ float slog[CC];

    ((float*)hbufA)[tid & 127] = 0.f;               // 512B = 128 floats
    if (tid < 128) ((float*)hbufB)[tid] = 0.f;

    const int wr_off = (tid >> 6) * 128
                     + (((((tid >> 3) & 7) + 2 * (tid >> 6)) & 7) << 4)
                     + ((tid & 7) << 1);
    int roff[8];
    #pragma unroll
    for (int i = 0; i < 8; ++i)
        roff[i] = kc * 128 + (((i + 2 * kc) & 7) << 4);

    __syncthreads();

    float hlast = 0.f;

#define SSTEP(HSRC, HDST, UVC, UVN, S_) {                                    \
        /* prefetch next step's uv (in-bounds row; value unused on last) */  \
        UVN = *(const _Float16*)(ubuf + ((((S_) + 1) & 63) << 9) + tid * 2); \
        float a0 = 0.f, a1 = 0.f, a2 = 0.f, a3 = 0.f;                        \
        _Pragma("unroll")                                                    \
        for (int i = 0; i < 8; ++i) {                                        \
            float4 hv = *(const float4*)(HSRC + roff[i]);                    \
            h2* hp = (h2*)&hv;                                               \
            _Pragma("unroll")                                                \
            for (int z = 0; z < 4; ++z) {                                    \
                a0 = dot2f(w[0][4*i+z], hp[z], a0);                          \
                a1 = dot2f(w[1][4*i+z], hp[z], a1);                          \
                a2 = dot2f(w[2][4*i+z], hp[z], a2);                          \
                a3 = dot2f(w[3][4*i+z], hp[z], a3);                          \
            }                                                                \
        }                                                                    \
        a0 = dpp_add4(a0); a1 = dpp_add4(a1);                                \
        a2 = dpp_add4(a2); a3 = dpp_add4(a3);                                \
        float v = (kc == 0) ? a0 : (kc == 1) ? a1 : (kc == 2) ? a2 : a3;     \
        const float hnew = fast_tanh(v + (float)UVC);                        \
        hlast = hnew;                                                        \
        *(_Float16*)(HDST + wr_off) = (_Float16)hnew;                        \
        __builtin_amdgcn_sched_barrier(0);                                   \
        asm volatile("s_waitcnt lgkmcnt(0)");                                \
        __builtin_amdgcn_s_barrier();                                        \
        __builtin_amdgcn_sched_barrier(0);                                   \
    }

    if (len2 > 0) {
        const char* ubase = (const char*)(u + ((size_t)b * TT + (TT - len2)) * HH);
        const int totbytes = len2 * 512;
        for (int c = 0; c * 64 < len2; ++c) {
            const int cbase = c * 32768;
            float4 stash[8];
            #pragma unroll
            for (int q = 0; q < 8; ++q) {
                int off = cbase + q * 4096 + tid * 16;
                off = (off > totbytes - 16) ? (totbytes - 16) : off;
                stash[q] = *(const float4*)(ubase + off);
            }
            #pragma unroll
            for (int q = 0; q < 8; ++q)
                *(float4*)(ubuf + q * 4096 + tid * 16) = stash[q];
            __syncthreads();
            const int steps = (len2 - c * 64 < 64) ? (len2 - c * 64) : 64;
            _Float16 uv0 = *(const _Float16*)(ubuf + tid * 2);
            _Float16 uv1;
            for (int s = 0; s < steps; s += 2) {
                SSTEP(hbufA, hbufB, uv0, uv1, s);       // even: A -> B
                SSTEP(hbufB, hbufA, uv1, uv0, s + 1);   // odd:  B -> A
            }
        }
    }

    // ---- fused MLP head + log_softmax (thread tid holds h[b][tid]) ----
    sh[tid] = hlast;
    __syncthreads();

    float acc[4];
    #pragma unroll
    for (int i = 0; i < 4; ++i) acc[i] = b0[tid + 256 * i];
    const float4* sh4 = (const float4*)sh;
    for (int k4 = 0; k4 < HH / 4; ++k4) {
        float4 hv = sh4[k4];
        #pragma unroll
        for (int i = 0; i < 4; ++i) {
            float4 wv = ((const float4*)(W0 + (size_t)(tid + 256 * i) * HH))[k4];
            acc[i] += wv.x * hv.x + wv.y * hv.y + wv.z * hv.z + wv.w * hv.w;
        }
    }
    #pragma unroll
    for (int i = 0; i < 4; ++i) sh1[tid + 256 * i] = fmaxf(acc[i], 0.f);
    __syncthreads();

    float pc[CC] = {0.f, 0.f, 0.f, 0.f, 0.f};
    for (int k = tid; k < MM; k += 256) {
        float hv = sh1[k];
        #pragma unroll
        for (int c = 0; c < CC; ++c) pc[c] += W1[(size_t)c * MM + k] * hv;
    }
    const int lane = tid & 63, wid = tid >> 6;
    #pragma unroll
    for (int c = 0; c < CC; ++c) {
        float v = pc[c];
        #pragma unroll
        for (int off = 32; off > 0; off >>= 1) v += __shfl_down(v, off, 64);
        if (lane == 0) sred[c][wid] = v;
    }
    __syncthreads();
    if (tid < CC) {
        float s = sred[tid][0] + sred[tid][1] + sred[tid][2] + sred[tid][3]
                + b1[tid];
        slog[tid] = fmaxf(s, 0.f);
    }
    __syncthreads();
    if (tid < CC) {
        float mx = slog[0];
        #pragma unroll
        for (int c = 1; c < CC; ++c) mx = fmaxf(mx, slog[c]);
        float se = 0.f;
        #pragma unroll
        for (int c = 0; c < CC; ++c) se += __expf(slog[c] - mx);
        out[(size_t)b * CC + tid] = slog[tid] - mx - __logf(se);
    }
}

// ---------------------------------------------------------------------------
extern "C" void kernel_launch(void* const* d_in, const int* in_sizes, int n_in,
                              void* d_out, int out_size, void* d_ws, size_t ws_size,
                              hipStream_t stream) {
    const int*   x       = (const int*)d_in[0];
    const int*   lengths = (const int*)d_in[1];
    const float* emb     = (const float*)d_in[2];
    const float* W_ih    = (const float*)d_in[3];
    const float* W_hh    = (const float*)d_in[4];
    const float* b_ih    = (const float*)d_in[5];
    const float* b_hh    = (const float*)d_in[6];
    const float* W0      = (const float*)d_in[7];
    const float* b0      = (const float*)d_in[8];
    const float* W1      = (const float*)d_in[9];
    const float* b1      = (const float*)d_in[10];
    float* out = (float*)d_out;

    // Workspace: u only — exactly BB*TT*HH*2 = 32 MiB.
    _Float16* u = (_Float16*)d_ws;

    k_embed   <<<(BB * TT) / 32, 256, 0, stream>>>(x, lengths, emb, W_ih, b_ih, b_hh, u);
    k_rnn_head<<<BB, 256, 0, stream>>>(lengths, W_hh, u, W0, b0, W1, b1, out);
}

// Round 8
// 383.121 us; speedup vs baseline: 3.0930x; 1.0505x over previous
//
#include <hip/hip_runtime.h>
#include <hip/hip_bf16.h>

#define BB 128
#define TT 512
#define EE 128
#define HH 256
#define MM 1024
#define CC 5

typedef _Float16 h2 __attribute__((ext_vector_type(2)));
typedef __fp16 f16x2 __attribute__((ext_vector_type(2)));
typedef __fp16 f16x8 __attribute__((ext_vector_type(8)));
typedef float  f32x4 __attribute__((ext_vector_type(4)));

__device__ inline h2 mkh2(float a, float b) {
    return __builtin_bit_cast(h2, __builtin_amdgcn_cvt_pkrtz(a, b));
}

// pack 8 f32 -> 8 f16 (one MFMA operand fragment)
__device__ inline f16x8 pack8(float4 lo, float4 hi) {
    union { f16x2 h[4]; f16x8 v; } u;
    u.h[0] = __builtin_amdgcn_cvt_pkrtz(lo.x, lo.y);
    u.h[1] = __builtin_amdgcn_cvt_pkrtz(lo.z, lo.w);
    u.h[2] = __builtin_amdgcn_cvt_pkrtz(hi.x, hi.y);
    u.h[3] = __builtin_amdgcn_cvt_pkrtz(hi.z, hi.w);
    return u.v;
}

__device__ inline float dot2f(h2 a, h2 b, float c) {
#if __has_builtin(__builtin_amdgcn_fdot2)
    return __builtin_amdgcn_fdot2(a, b, c, false);
#else
    return c + (float)a.x * (float)b.x + (float)a.y * (float)b.y;
#endif
}

// Quad butterfly sum via DPP (VALU pipe, no LDS traffic).
__device__ inline float dpp_add4(float x) {
    int t = __builtin_amdgcn_update_dpp(0, __builtin_bit_cast(int, x), 0xB1, 0xF, 0xF, true);
    x += __builtin_bit_cast(float, t);
    t = __builtin_amdgcn_update_dpp(0, __builtin_bit_cast(int, x), 0x4E, 0xF, 0xF, true);
    x += __builtin_bit_cast(float, t);
    return x;
}

__device__ inline float fast_tanh(float x) {
    float e = __expf(2.0f * x);
    return 1.0f - 2.0f / (e + 1.0f);
}

// ---------------------------------------------------------------------------
// K (R14): single fused kernel. One workgroup (256 thr) per batch element.
// Per 64-step chunk:
//   PHASE A (chunk GEMM, the verified k_embed plumbing extended to 64 tokens):
//     gather emb[x[t]] rows -> f16 ldsA[64][128] -> MFMA (W_ih frags resident,
//     bias in C-init) -> D (masked to 0 for t < T-len) -> ubuf[64][256] f16.
//   PHASE B: the verified R13 serial VALU scan over ubuf (split-K(4) + DPP,
//     uv prefetched 1 step ahead, lgkm-only barrier, x2 unrolled ping-pong).
// k_embed kernel + 32MiB u workspace DELETED: its ~70us wall time was
// structural (2048 tiny latency-chain blocks), insensitive to work (R13
// early-exit bought ~0). Chunk-GEMM adds ~1.5us x 8 chunks serially instead.
// u numerics identical: same f16 rounding of bias + emb@W_ih^T, same mask.
// MFMA layouts (m89/m120-verified): A[m=lane&15][k=quad*8+j],
// B[k=quad*8+j][n=lane&15], D col=lane&15 row=quad*4+reg.
// ---------------------------------------------------------------------------
__global__ __launch_bounds__(256, 1)
void k_fused(const int* __restrict__ x, const int* __restrict__ lengths,
             const float* __restrict__ emb,
             const float* __restrict__ W_ih, const float* __restrict__ W_hh,
             const float* __restrict__ b_ih, const float* __restrict__ b_hh,
             const float* __restrict__ W0, const float* __restrict__ b0,
             const float* __restrict__ W1, const float* __restrict__ b1,
             float* __restrict__ out)
{
    const int b   = blockIdx.x;
    const int tid = threadIdx.x;
    const int kc  = tid & 3;
    const int g   = tid >> 2;
    const int wv   = tid >> 6;
    const int lane = tid & 63;
    const int l15  = lane & 15;
    const int quad = lane >> 4;
    const int len  = lengths[b];
    const int len2 = (len + 1) & ~1;              // even-rounded (<= TT)
    const int start = TT - len;                   // first active t

    // ---- resident weights ----
    // W_hh rows for the scan (verified R1 layout)
    h2 w[4][32];
    #pragma unroll
    for (int m = 0; m < 4; ++m) {
        const float4* wr = (const float4*)(W_hh + (size_t)(4*g + m) * HH + kc*64);
        #pragma unroll
        for (int q = 0; q < 16; ++q) {
            float4 v = wr[q];
            w[m][2*q]   = mkh2(v.x, v.y);
            w[m][2*q+1] = mkh2(v.z, v.w);
        }
    }
    // W_ih B-frags for the chunk GEMM (verified k_embed layout):
    // n = 64*wv + 16*ct + l15, k = 32*kc2 + 8*quad + j
    f16x8 bfih[4][4];
    float bias[4];
    #pragma unroll
    for (int ct = 0; ct < 4; ++ct) {
        const int n = 64 * wv + 16 * ct + l15;
        const float* wp = W_ih + (size_t)n * EE;
        #pragma unroll
        for (int kk = 0; kk < 4; ++kk) {
            const float4* p = (const float4*)(wp + 32 * kk + 8 * quad);
            bfih[ct][kk] = pack8(p[0], p[1]);
        }
        bias[ct] = b_ih[n] + b_hh[n];
    }

    __shared__ __align__(16) char hbufA[512];       // 256 f16 (b128-read)
    __shared__ __align__(16) char hbufB[512];
    __shared__ __align__(16) char ubuf[64 * 512];   // 64 steps x 256ch x 2B
    __shared__ __align__(16) char ldsA[64 * 256];   // 16KB f16 emb A-stage
    __shared__ __align__(16) float sh[HH];          // head: h row (f32)
    __shared__ __align__(16) float sh1[MM];         // head: relu(h@W0^T+b0)
    __shared__ float sred[CC][4];
    __shared__ float slog[CC];

    ((float*)hbufA)[tid & 127] = 0.f;               // 512B = 128 floats
    if (tid < 128) ((float*)hbufB)[tid] = 0.f;

    const int wr_off = (tid >> 6) * 128
                     + (((((tid >> 3) & 7) + 2 * (tid >> 6)) & 7) << 4)
                     + ((tid & 7) << 1);
    int roff[8];
    #pragma unroll
    for (int i = 0; i < 8; ++i)
        roff[i] = kc * 128 + (((i + 2 * kc) & 7) << 4);

    __syncthreads();

    float hlast = 0.f;

#define SSTEP(HSRC, HDST, UVC, UVN, S_) {                                    \
        UVN = *(const _Float16*)(ubuf + ((((S_) + 1) & 63) << 9) + tid * 2); \
        float a0 = 0.f, a1 = 0.f, a2 = 0.f, a3 = 0.f;                        \
        _Pragma("unroll")                                                    \
        for (int i = 0; i < 8; ++i) {                                        \
            float4 hv = *(const float4*)(HSRC + roff[i]);                    \
            h2* hp = (h2*)&hv;                                               \
            _Pragma("unroll")                                                \
            for (int z = 0; z < 4; ++z) {                                    \
                a0 = dot2f(w[0][4*i+z], hp[z], a0);                          \
                a1 = dot2f(w[1][4*i+z], hp[z], a1);                          \
                a2 = dot2f(w[2][4*i+z], hp[z], a2);                          \
                a3 = dot2f(w[3][4*i+z], hp[z], a3);                          \
            }                                                                \
        }                                                                    \
        a0 = dpp_add4(a0); a1 = dpp_add4(a1);                                \
        a2 = dpp_add4(a2); a3 = dpp_add4(a3);                                \
        float v = (kc == 0) ? a0 : (kc == 1) ? a1 : (kc == 2) ? a2 : a3;     \
        const float hnew = fast_tanh(v + (float)UVC);                        \
        hlast = hnew;                                                        \
        *(_Float16*)(HDST + wr_off) = (_Float16)hnew;                        \
        __builtin_amdgcn_sched_barrier(0);                                   \
        asm volatile("s_waitcnt lgkmcnt(0)");                                \
        __builtin_amdgcn_s_barrier();                                        \
        __builtin_amdgcn_sched_barrier(0);                                   \
    }

    if (len2 > 0) {
        for (int c = 0; c * 64 < len2; ++c) {
            const int tbase = (TT - len2) + 64 * c;

            // ---- PHASE A: chunk GEMM -> ubuf[0..63][256] ----
            // stage 64 emb rows (clamped token index; OOB rows never consumed)
            #pragma unroll
            for (int half = 0; half < 2; ++half) {
                const int r = (tid >> 3) + 32 * half;   // token row 0..63
                const int s = tid & 7;                  // 16-float segment
                int tg = tbase + r;
                tg = (tg < TT - 1) ? tg : (TT - 1);
                const int tok = x[(size_t)b * TT + tg];
                const float4* ep = (const float4*)(emb + (size_t)tok * EE + 16 * s);
                float4 va = ep[0], vb = ep[1], vc = ep[2], vd = ep[3];
                *(f16x8*)(ldsA + r * 256 + 32 * s)      = pack8(va, vb);
                *(f16x8*)(ldsA + r * 256 + 32 * s + 16) = pack8(vc, vd);
            }
            __syncthreads();

            f32x4 acc[4][4];                            // [rt][ct]
            #pragma unroll
            for (int rt = 0; rt < 4; ++rt)
                #pragma unroll
                for (int ct = 0; ct < 4; ++ct)
                    acc[rt][ct] = (f32x4){bias[ct], bias[ct], bias[ct], bias[ct]};

            #pragma unroll
            for (int kk = 0; kk < 4; ++kk) {
                const int ko = (32 * kk + 8 * quad) * 2;
                f16x8 af0 = *(const f16x8*)(ldsA + (l15)      * 256 + ko);
                f16x8 af1 = *(const f16x8*)(ldsA + (16 + l15) * 256 + ko);
                f16x8 af2 = *(const f16x8*)(ldsA + (32 + l15) * 256 + ko);
                f16x8 af3 = *(const f16x8*)(ldsA + (48 + l15) * 256 + ko);
                #pragma unroll
                for (int ct = 0; ct < 4; ++ct) {
                    acc[0][ct] = __builtin_amdgcn_mfma_f32_16x16x32_f16(af0, bfih[ct][kk], acc[0][ct], 0, 0, 0);
                    acc[1][ct] = __builtin_amdgcn_mfma_f32_16x16x32_f16(af1, bfih[ct][kk], acc[1][ct], 0, 0, 0);
                    acc[2][ct] = __builtin_amdgcn_mfma_f32_16x16x32_f16(af2, bfih[ct][kk], acc[2][ct], 0, 0, 0);
                    acc[3][ct] = __builtin_amdgcn_mfma_f32_16x16x32_f16(af3, bfih[ct][kk], acc[3][ct], 0, 0, 0);
                }
            }

            // D -> ubuf [token][ch] f16, masked to 0 for inactive t
            #pragma unroll
            for (int rt = 0; rt < 4; ++rt) {
                #pragma unroll
                for (int ct = 0; ct < 4; ++ct) {
                    const int chb = (64 * wv + 16 * ct + l15) * 2;
                    #pragma unroll
                    for (int rg = 0; rg < 4; ++rg) {
                        const int tok = 16 * rt + 4 * quad + rg;
                        const bool act = (tbase + tok) >= start;
                        const float dv = act ? acc[rt][ct][rg] : 0.f;
                        *(_Float16*)(ubuf + tok * 512 + chb) = (_Float16)dv;
                    }
                }
            }
            __syncthreads();

            // ---- PHASE B: serial scan over this chunk ----
            const int steps = (len2 - c * 64 < 64) ? (len2 - c * 64) : 64;
            _Float16 uv0 = *(const _Float16*)(ubuf + tid * 2);
            _Float16 uv1;
            for (int s = 0; s < steps; s += 2) {
                SSTEP(hbufA, hbufB, uv0, uv1, s);       // even: A -> B
                SSTEP(hbufB, hbufA, uv1, uv0, s + 1);   // odd:  B -> A
            }
        }
    }

    // ---- fused MLP head + log_softmax (thread tid holds h[b][tid]) ----
    sh[tid] = hlast;
    __syncthreads();

    float acc[4];
    #pragma unroll
    for (int i = 0; i < 4; ++i) acc[i] = b0[tid + 256 * i];
    const float4* sh4 = (const float4*)sh;
    for (int k4 = 0; k4 < HH / 4; ++k4) {
        float4 hv = sh4[k4];
        #pragma unroll
        for (int i = 0; i < 4; ++i) {
            float4 wv4 = ((const float4*)(W0 + (size_t)(tid + 256 * i) * HH))[k4];
            acc[i] += wv4.x * hv.x + wv4.y * hv.y + wv4.z * hv.z + wv4.w * hv.w;
        }
    }
    #pragma unroll
    for (int i = 0; i < 4; ++i) sh1[tid + 256 * i] = fmaxf(acc[i], 0.f);
    __syncthreads();

    float pc[CC] = {0.f, 0.f, 0.f, 0.f, 0.f};
    for (int k = tid; k < MM; k += 256) {
        float hv = sh1[k];
        #pragma unroll
        for (int c = 0; c < CC; ++c) pc[c] += W1[(size_t)c * MM + k] * hv;
    }
    const int lane6 = tid & 63, wid = tid >> 6;
    #pragma unroll
    for (int c = 0; c < CC; ++c) {
        float v = pc[c];
        #pragma unroll
        for (int off = 32; off > 0; off >>= 1) v += __shfl_down(v, off, 64);
        if (lane6 == 0) sred[c][wid] = v;
    }
    __syncthreads();
    if (tid < CC) {
        float s = sred[tid][0] + sred[tid][1] + sred[tid][2] + sred[tid][3]
                + b1[tid];
        slog[tid] = fmaxf(s, 0.f);
    }
    __syncthreads();
    if (tid < CC) {
        float mx = slog[0];
        #pragma unroll
        for (int c = 1; c < CC; ++c) mx = fmaxf(mx, slog[c]);
        float se = 0.f;
        #pragma unroll
        for (int c = 0; c < CC; ++c) se += __expf(slog[c] - mx);
        out[(size_t)b * CC + tid] = slog[tid] - mx - __logf(se);
    }
}

// ---------------------------------------------------------------------------
extern "C" void kernel_launch(void* const* d_in, const int* in_sizes, int n_in,
                              void* d_out, int out_size, void* d_ws, size_t ws_size,
                              hipStream_t stream) {
    const int*   x       = (const int*)d_in[0];
    const int*   lengths = (const int*)d_in[1];
    const float* emb     = (const float*)d_in[2];
    const float* W_ih    = (const float*)d_in[3];
    const float* W_hh    = (const float*)d_in[4];
    const float* b_ih    = (const float*)d_in[5];
    const float* b_hh    = (const float*)d_in[6];
    const float* W0      = (const float*)d_in[7];
    const float* b0      = (const float*)d_in[8];
    const float* W1      = (const float*)d_in[9];
    const float* b1      = (const float*)d_in[10];
    float* out = (float*)d_out;

    // workspace unused (u eliminated)
    (void)d_ws; (void)ws_size;

    k_fused<<<BB, 256, 0, stream>>>(x, lengths, emb, W_ih, W_hh,
                                    b_ih, b_hh, W0, b0, W1, b1, out);
}